// Round 11
// baseline (102.647 us; speedup 1.0000x reference)
//
#include <hip/hip_runtime.h>
#include <hip/hip_bf16.h>

// ---------------------------------------------------------------------------
// TT-linear, rank-64 factorized, 3 launches:
//   tt_chain_fused : cores -> A4f (MFMA-fragment-ordered bf16), B4t (4096x64)
//   GEMM1          : zb[8192x64] = x @ A4; 512 x 1024, 2 blocks/CU,
//                    depth-4 register prefetch pipeline (latency fix)
//   GEMM2          : out = zb @ B4t^T + bias, K=64; LDS-staged epilogue (r8)
// HBM floor: read x 131 MB (L3-cacheable) + write out 134 MB ~= 42 us.
// ---------------------------------------------------------------------------

typedef __attribute__((ext_vector_type(8))) short short8;
typedef __attribute__((ext_vector_type(4))) short s16x4;
typedef __attribute__((ext_vector_type(4))) float f32x4;

__device__ __forceinline__ short f2bf(float f) {
    union { float f; unsigned u; } c; c.f = f;
    unsigned u = c.u;
    unsigned r = (u + 0x7fffu + ((u >> 16) & 1u)) >> 16;  // RNE
    return (short)r;
}

// ---------------- chain: all 6 stages, 1 launch, 1536 x 256 (proven r10) ----
__global__ __launch_bounds__(256) void tt_chain_fused(
    const float* __restrict__ c0, const float* __restrict__ c1,
    const float* __restrict__ c2, const float* __restrict__ c3,
    const float* __restrict__ c4, const float* __restrict__ c5,
    const float* __restrict__ c6, const float* __restrict__ c7,
    short* __restrict__ A4f, short* __restrict__ B4t) {
    __shared__ float sm[1024];
    const int t = threadIdx.x;
    if (blockIdx.x < 1024) {
        const int bid = blockIdx.x;
        const int i = bid >> 1;          // A3 row
        const int a2r = bid >> 4;        // A2 row
        float* A2r_ = sm;                // 64
        float* A3r_ = sm + 64;           // 64
        if (t < 64) {
            const int i1 = a2r >> 3, d1 = a2r & 7;
            float acc = 0.f;
            for (int r = 0; r < 64; ++r)
                acc += c0[i1 * 64 + r] * c1[(r * 8 + d1) * 64 + t];
            A2r_[t] = acc;
        }
        __syncthreads();
        if (t < 64) {
            const int d2 = i & 7;
            float acc = 0.f;
            for (int r = 0; r < 64; ++r)
                acc += A2r_[r] * c2[(r * 8 + d2) * 64 + t];
            A3r_[t] = acc;
        }
        __syncthreads();
        {
            const int kk = t >> 6, s = t & 63;
            const int k = (bid << 2) + kk, d3 = k & 7;
            float acc = 0.f;
            for (int r = 0; r < 64; ++r)
                acc += A3r_[r] * c3[(r * 8 + d3) * 64 + s];
            A4f[(((k >> 5) * 4 + (s >> 4)) << 9) + (((k >> 3) & 3) << 7) +
                ((s & 15) << 3) + (k & 7)] = f2bf(acc);
        }
    } else {
        const int cb = blockIdx.x - 1024;       // [0,512)
        const int d4 = cb & 7, jgrp = cb >> 3;  // jgrp in [0,64)
        const int d5 = jgrp >> 3;
        const int d6 = jgrp & 7;
        float* B6l = sm;         // [q6*8 + jj] = B6[q6][d6*8+jj]
        float* B5l = sm + 512;   // [q5*8 + jj] = B5[q5][jgrp*8+jj]
        for (int o = t; o < 512; o += 256) {
            const int q6 = o >> 3, jj = o & 7;
            float acc = 0.f;
            for (int q7 = 0; q7 < 64; ++q7)
                acc += c6[(q6 * 8 + d6) * 64 + q7] * c7[q7 * 8 + jj];
            B6l[o] = acc;
        }
        __syncthreads();
        for (int o = t; o < 512; o += 256) {
            const int q5 = o >> 3, jj = o & 7;
            float acc = 0.f;
            for (int q6 = 0; q6 < 64; ++q6)
                acc += c5[(q5 * 8 + d5) * 64 + q6] * B6l[q6 * 8 + jj];
            B5l[o] = acc;
        }
        __syncthreads();
        for (int o = t; o < 512; o += 256) {
            const int nl = o >> 6, r4 = o & 63;
            float acc = 0.f;
            for (int q5 = 0; q5 < 64; ++q5)
                acc += c4[(r4 * 8 + d4) * 64 + q5] * B5l[q5 * 8 + nl];
            const int n = d4 * 512 + jgrp * 8 + nl;
            B4t[n * 64 + r4] = f2bf(acc);
        }
    }
}

// ---------------- GEMM1: zb = f2bf(x @ A4), depth-4 prefetch pipeline -------
// 512 blocks x 1024 threads (16 waves), 2 blocks/CU.  Wave w owns k-tiles
// t = w + 16*it (it<8 for w<13, it<7 for w>=13; 125 = 13*8 + 3*7).
// Named register buffers (no runtime indexing -> no scratch), prefetch issued
// before the MFMA cluster so ~4 tiles (128B/lane-grp) stay in flight.
__global__ __launch_bounds__(1024, 8) void gemm1_v3(
    const float* __restrict__ x, const short* __restrict__ A4f,
    short* __restrict__ zb) {
    __shared__ float zsm[16 * 1024];  // 64 KB: [wave][row16][col64]
    const int tid = threadIdx.x, wave = tid >> 6, lane = tid & 63;
    const int m0 = blockIdx.x << 4;
    const int r16 = lane & 15, hi = lane >> 4, kq = hi << 3;
    const float* xp = x + (long)(m0 + r16) * 4000 + kq;
    const short* a4p = A4f + (lane << 3);

    f32x4 acc[4] = {};
    f32x4 A0, B0, A1, B1, A2, B2, A3, B3;
    {   // prologue: tiles wave, wave+16, wave+32, wave+48 (all < 125)
        const float* p0 = xp + (wave << 5);
        const float* p1 = xp + ((wave + 16) << 5);
        const float* p2 = xp + ((wave + 32) << 5);
        const float* p3 = xp + ((wave + 48) << 5);
        A0 = *(const f32x4*)p0; B0 = *(const f32x4*)(p0 + 4);
        A1 = *(const f32x4*)p1; B1 = *(const f32x4*)(p1 + 4);
        A2 = *(const f32x4*)p2; B2 = *(const f32x4*)(p2 + 4);
        A3 = *(const f32x4*)p3; B3 = *(const f32x4*)(p3 + 4);
    }
#define G1_STEP(IT, UA, UB)                                                   \
    if ((IT) < 7 || wave < 13) {                                              \
        const int t_ = wave + ((IT) << 4);                                    \
        short8 a_;                                                            \
        a_[0] = f2bf(UA[0]); a_[1] = f2bf(UA[1]);                             \
        a_[2] = f2bf(UA[2]); a_[3] = f2bf(UA[3]);                             \
        a_[4] = f2bf(UB[0]); a_[5] = f2bf(UB[1]);                             \
        a_[6] = f2bf(UB[2]); a_[7] = f2bf(UB[3]);                             \
        if ((IT) < 4) {  /* prefetch tile t_+64 into the same buffer */       \
            const int pf_ = t_ + 64;                                          \
            if (pf_ < 125) {                                                  \
                const float* pp_ = xp + (pf_ << 5);                           \
                UA = *(const f32x4*)pp_; UB = *(const f32x4*)(pp_ + 4);       \
            }                                                                 \
        }                                                                     \
        acc[0] = __builtin_amdgcn_mfma_f32_16x16x32_bf16(                     \
            a_, *(const short8*)(a4p + (((t_ << 2) + 0) << 9)), acc[0], 0, 0, 0); \
        acc[1] = __builtin_amdgcn_mfma_f32_16x16x32_bf16(                     \
            a_, *(const short8*)(a4p + (((t_ << 2) + 1) << 9)), acc[1], 0, 0, 0); \
        acc[2] = __builtin_amdgcn_mfma_f32_16x16x32_bf16(                     \
            a_, *(const short8*)(a4p + (((t_ << 2) + 2) << 9)), acc[2], 0, 0, 0); \
        acc[3] = __builtin_amdgcn_mfma_f32_16x16x32_bf16(                     \
            a_, *(const short8*)(a4p + (((t_ << 2) + 3) << 9)), acc[3], 0, 0, 0); \
    }
    G1_STEP(0, A0, B0)
    G1_STEP(1, A1, B1)
    G1_STEP(2, A2, B2)
    G1_STEP(3, A3, B3)
    G1_STEP(4, A0, B0)
    G1_STEP(5, A1, B1)
    G1_STEP(6, A2, B2)
    G1_STEP(7, A3, B3)
#undef G1_STEP

    // C/D layout: col = f*16 + (lane&15), row = (lane>>4)*4 + u
    const int prow = hi << 2;
#pragma unroll
    for (int f = 0; f < 4; ++f)
#pragma unroll
        for (int u = 0; u < 4; ++u)
            zsm[wave * 1024 + (prow + u) * 64 + f * 16 + r16] = acc[f][u];
    __syncthreads();
    if (tid < 256) {
        const f32x4* zp = (const f32x4*)zsm;  // 256 f32x4 per wave-slab
        f32x4 s = zp[tid];
#pragma unroll
        for (int w = 1; w < 16; ++w) s += zp[w * 256 + tid];
        s16x4 o;
#pragma unroll
        for (int u = 0; u < 4; ++u) o[u] = f2bf(s[u]);
        const int orow = tid >> 4, ocol = (tid & 15) << 2;
        *(s16x4*)(zb + (m0 + orow) * 64 + ocol) = o;
    }
}

// ---------------- GEMM2: C = zb(8192xK) * B4t(4096xK)^T + bias (proven r8) --
#define BM 128
#define BN 128
#define BK 32

template <int K>
__global__ __launch_bounds__(256) void gemm_bias_kernel(
    const short* __restrict__ A,    // M x K bf16
    const short* __restrict__ Bt,   // N x K bf16
    const float* __restrict__ bias,
    float* __restrict__ C) {
    constexpr int N = 4096;
    __shared__ __align__(16) char smem[16384];  // staging (8K+8K), epilogue 16K
    short* As = (short*)smem;
    short* Bs = (short*)(smem + 8192);
    float* eps = (float*)smem;

    const int tid  = threadIdx.x;
    const int wave = tid >> 6;
    const int lane = tid & 63;

    const int bid = blockIdx.x;
    const int wg  = (bid & 7) * 256 + (bid >> 3);  // 2048 % 8 == 0, bijective
    const int m0 = (wg >> 5) * BM;
    const int n0 = (wg & 31) * BN;

    const int c0i = tid;
    const int c1i = 256 + tid;
    const short* gA0 = A  + (m0 + (c0i >> 2)) * K + ((c0i & 3) << 3);
    const short* gA1 = A  + (m0 + (c1i >> 2)) * K + ((c1i & 3) << 3);
    const short* gB0 = Bt + (n0 + (c0i >> 2)) * K + ((c0i & 3) << 3);
    const short* gB1 = Bt + (n0 + (c1i >> 2)) * K + ((c1i & 3) << 3);
    short* lA0 = As + wave * 512;
    short* lA1 = As + 2048 + wave * 512;
    short* lB0 = Bs + wave * 512;
    short* lB1 = Bs + 2048 + wave * 512;

    const int wr = (wave >> 1) << 6;
    const int wc = (wave & 1) << 6;
    const int r16 = lane & 15;
    const int hi  = lane >> 4;
    const int kq  = hi << 3;

    f32x4 acc[4][4] = {};

    for (int kt = 0; kt < K / BK; ++kt) {
        __builtin_amdgcn_global_load_lds((const __attribute__((address_space(1))) void*)gA0,
                                         (__attribute__((address_space(3))) void*)lA0, 16, 0, 0);
        __builtin_amdgcn_global_load_lds((const __attribute__((address_space(1))) void*)gA1,
                                         (__attribute__((address_space(3))) void*)lA1, 16, 0, 0);
        __builtin_amdgcn_global_load_lds((const __attribute__((address_space(1))) void*)gB0,
                                         (__attribute__((address_space(3))) void*)lB0, 16, 0, 0);
        __builtin_amdgcn_global_load_lds((const __attribute__((address_space(1))) void*)gB1,
                                         (__attribute__((address_space(3))) void*)lB1, 16, 0, 0);
        gA0 += BK; gA1 += BK; gB0 += BK; gB1 += BK;
        __syncthreads();

        short8 a[4], b[4];
#pragma unroll
        for (int f = 0; f < 4; ++f) {
            a[f] = *(const short8*)(As + (wr + f * 16 + r16) * BK + kq);
            b[f] = *(const short8*)(Bs + (wc + f * 16 + r16) * BK + kq);
        }
#pragma unroll
        for (int i = 0; i < 4; ++i)
#pragma unroll
            for (int j = 0; j < 4; ++j)
                acc[i][j] = __builtin_amdgcn_mfma_f32_16x16x32_bf16(
                    a[i], b[j], acc[i][j], 0, 0, 0);
        __syncthreads();
    }

    // ---- epilogue: LDS transpose (barriered) -> 256B-contiguous stores -----
    float* slab = eps + wave * 1024;  // per-wave 4 KB slab
    const f32x4 bzv = *(const f32x4*)(bias + n0 + wc + (r16 << 2));
#pragma unroll
    for (int i = 0; i < 4; ++i) {
        __syncthreads();   // previous iteration's reads (and K-loop) complete
#pragma unroll
        for (int j = 0; j < 4; ++j)
#pragma unroll
            for (int u = 0; u < 4; ++u)
                slab[((hi << 2) + u) * 64 + j * 16 + r16] = acc[i][j][u];
        __syncthreads();   // cross-lane transpose: writes visible to reads
#pragma unroll
        for (int c = 0; c < 4; ++c) {
            const int lrow = (c << 2) + hi;                 // 0..15
            f32x4 v = *(const f32x4*)(slab + lrow * 64 + (r16 << 2));
            v += bzv;
            const long row = m0 + wr + i * 16 + lrow;
            *(f32x4*)(C + row * N + n0 + wc + (r16 << 2)) = v;
        }
    }
}

// ---------------------------------------------------------------------------
extern "C" void kernel_launch(void* const* d_in, const int* in_sizes, int n_in,
                              void* d_out, int out_size, void* d_ws, size_t ws_size,
                              hipStream_t stream) {
    const float* x    = (const float*)d_in[0];
    const float* c0   = (const float*)d_in[1];
    const float* c1   = (const float*)d_in[2];
    const float* c2   = (const float*)d_in[3];
    const float* c3   = (const float*)d_in[4];
    const float* c4   = (const float*)d_in[5];
    const float* c5   = (const float*)d_in[6];
    const float* c6   = (const float*)d_in[7];
    const float* c7   = (const float*)d_in[8];
    const float* bias = (const float*)d_in[9];
    float* out = (float*)d_out;

    char* ws = (char*)d_ws;
    short* zb  = (short*)ws;                               // 8192*64*2 = 1 MiB
    short* A4f = (short*)(ws + (1u << 20));                // 512 KiB (frag-ordered)
    short* B4t = (short*)(ws + (1u << 20) + (512u << 10)); // 4096*64*2 = 512 KiB

    tt_chain_fused<<<1536, 256, 0, stream>>>(c0, c1, c2, c3, c4, c5, c6, c7,
                                             A4f, B4t);
    gemm1_v3<<<512, 1024, 0, stream>>>(x, A4f, zb);
    gemm_bias_kernel<64><<<2048, 256, 0, stream>>>(zb, B4t, bias, out);
}

// Round 12
// 82.458 us; speedup vs baseline: 1.2448x; 1.2448x over previous
//
#include <hip/hip_runtime.h>
#include <hip/hip_bf16.h>

// ---------------------------------------------------------------------------
// TT-linear, rank-64 factorized, 3 launches (best-known config, r8+r10):
//   tt_chain_fused : cores -> A4f (MFMA-fragment-ordered bf16), B4t (4096x64)
//                    [single launch, 1536 wide blocks; bit-identical to the
//                     proven 3-launch chain]
//   GEMM1 (r8)     : zb[8192x64] = x @ A4; 512 x 1024, 2 blocks/CU (45 VGPR),
//                    TLP-saturated streaming reads of x
//   GEMM2 (r8)     : out = zb @ B4t^T + bias, K=64; global_load_lds staging,
//                    barriered LDS-transpose epilogue (256B store segments)
// HBM floor: read x 131 MB + write out 134 MB ~= 42 us.
// Lesson bank: no nt hints (r10: +10us); no launch_bounds-forced pipelines
// (r11: VGPR spill, +15us); no 2-block chains (r3); no barrier-per-2-MFMA
// fusion (r9); occupancy arithmetic before fusing (r5).
// ---------------------------------------------------------------------------

typedef __attribute__((ext_vector_type(8))) short short8;
typedef __attribute__((ext_vector_type(4))) short s16x4;
typedef __attribute__((ext_vector_type(4))) float f32x4;

__device__ __forceinline__ short f2bf(float f) {
    union { float f; unsigned u; } c; c.f = f;
    unsigned u = c.u;
    unsigned r = (u + 0x7fffu + ((u >> 16) & 1u)) >> 16;  // RNE
    return (short)r;
}

// ---------------- chain: all 6 stages, 1 launch, 1536 x 256 (proven r10) ----
// A-side blocks [0,1024): block bid covers k = bid*4..+4 (A2/A3 rows
//   recomputed in LDS; identical summation order to the 3-launch chain).
//   A4f: value A4[k][s] at [((k>>5)*4+(s>>4))*512 + ((k>>3)&3)*128 + (s&15)*8 + (k&7)]
//   so gemm1's b-frag load for (tile t, f) is lane-contiguous: A4f+(t*4+f)*512+lane*8
// B-side blocks [1024,1536): cb = bid-1024; d4 = cb&7, jgrp = cb>>3;
//   covers n = d4*512 + jgrp*8 + (0..8), all 64 ranks r4 -> B4t[n*64+r4]
__global__ __launch_bounds__(256) void tt_chain_fused(
    const float* __restrict__ c0, const float* __restrict__ c1,
    const float* __restrict__ c2, const float* __restrict__ c3,
    const float* __restrict__ c4, const float* __restrict__ c5,
    const float* __restrict__ c6, const float* __restrict__ c7,
    short* __restrict__ A4f, short* __restrict__ B4t) {
    __shared__ float sm[1024];
    const int t = threadIdx.x;
    if (blockIdx.x < 1024) {
        const int bid = blockIdx.x;
        const int i = bid >> 1;          // A3 row
        const int a2r = bid >> 4;        // A2 row
        float* A2r_ = sm;                // 64
        float* A3r_ = sm + 64;           // 64
        if (t < 64) {
            const int i1 = a2r >> 3, d1 = a2r & 7;
            float acc = 0.f;
            for (int r = 0; r < 64; ++r)
                acc += c0[i1 * 64 + r] * c1[(r * 8 + d1) * 64 + t];
            A2r_[t] = acc;
        }
        __syncthreads();
        if (t < 64) {
            const int d2 = i & 7;
            float acc = 0.f;
            for (int r = 0; r < 64; ++r)
                acc += A2r_[r] * c2[(r * 8 + d2) * 64 + t];
            A3r_[t] = acc;
        }
        __syncthreads();
        {
            const int kk = t >> 6, s = t & 63;
            const int k = (bid << 2) + kk, d3 = k & 7;
            float acc = 0.f;
            for (int r = 0; r < 64; ++r)
                acc += A3r_[r] * c3[(r * 8 + d3) * 64 + s];
            A4f[(((k >> 5) * 4 + (s >> 4)) << 9) + (((k >> 3) & 3) << 7) +
                ((s & 15) << 3) + (k & 7)] = f2bf(acc);
        }
    } else {
        const int cb = blockIdx.x - 1024;       // [0,512)
        const int d4 = cb & 7, jgrp = cb >> 3;  // jgrp in [0,64)
        const int d5 = jgrp >> 3;
        const int d6 = jgrp & 7;
        float* B6l = sm;         // [q6*8 + jj] = B6[q6][d6*8+jj]
        float* B5l = sm + 512;   // [q5*8 + jj] = B5[q5][jgrp*8+jj]
        for (int o = t; o < 512; o += 256) {
            const int q6 = o >> 3, jj = o & 7;
            float acc = 0.f;
            for (int q7 = 0; q7 < 64; ++q7)
                acc += c6[(q6 * 8 + d6) * 64 + q7] * c7[q7 * 8 + jj];
            B6l[o] = acc;
        }
        __syncthreads();
        for (int o = t; o < 512; o += 256) {
            const int q5 = o >> 3, jj = o & 7;
            float acc = 0.f;
            for (int q6 = 0; q6 < 64; ++q6)
                acc += c5[(q5 * 8 + d5) * 64 + q6] * B6l[q6 * 8 + jj];
            B5l[o] = acc;
        }
        __syncthreads();
        for (int o = t; o < 512; o += 256) {
            const int nl = o >> 6, r4 = o & 63;
            float acc = 0.f;
            for (int q5 = 0; q5 < 64; ++q5)
                acc += c4[(r4 * 8 + d4) * 64 + q5] * B5l[q5 * 8 + nl];
            const int n = d4 * 512 + jgrp * 8 + nl;
            B4t[n * 64 + r4] = f2bf(acc);
        }
    }
}

// ---------------- GEMM1: zb = f2bf(x @ A4), 512 blocks x 1024 threads -------
// (r8 proven verbatim.) Block owns 16 rows; 16 waves split the 125 k-tiles
// (4000 = 125*32); f32 partials reduced through 64 KB LDS.
// 45 VGPR < 64 -> true 2 blocks/CU (32 waves), TLP saturates HBM reads.
__global__ __launch_bounds__(1024, 8) void gemm1_v2(
    const float* __restrict__ x, const short* __restrict__ A4f,
    short* __restrict__ zb) {
    __shared__ float zsm[16 * 1024];  // 64 KB: [wave][row16][col64]
    const int tid = threadIdx.x, wave = tid >> 6, lane = tid & 63;
    const int m0 = blockIdx.x << 4;
    const int r16 = lane & 15, hi = lane >> 4, kq = hi << 3;
    const float* xp = x + (long)(m0 + r16) * 4000 + kq;
    const short* a4p = A4f + (lane << 3);

    f32x4 acc[4] = {};
#pragma unroll 2
    for (int t = wave; t < 125; t += 16) {
        const int k0 = t << 5;
        f32x4 u0 = *(const f32x4*)(xp + k0);
        f32x4 u1 = *(const f32x4*)(xp + k0 + 4);
        short8 a;
        a[0] = f2bf(u0[0]); a[1] = f2bf(u0[1]);
        a[2] = f2bf(u0[2]); a[3] = f2bf(u0[3]);
        a[4] = f2bf(u1[0]); a[5] = f2bf(u1[1]);
        a[6] = f2bf(u1[2]); a[7] = f2bf(u1[3]);
#pragma unroll
        for (int f = 0; f < 4; ++f) {
            short8 b = *(const short8*)(a4p + (((t << 2) + f) << 9));
            acc[f] = __builtin_amdgcn_mfma_f32_16x16x32_bf16(a, b, acc[f], 0, 0, 0);
        }
    }
    // C/D layout: col = f*16 + (lane&15), row = (lane>>4)*4 + u
    const int prow = hi << 2;
#pragma unroll
    for (int f = 0; f < 4; ++f)
#pragma unroll
        for (int u = 0; u < 4; ++u)
            zsm[wave * 1024 + (prow + u) * 64 + f * 16 + r16] = acc[f][u];
    __syncthreads();
    if (tid < 256) {
        const f32x4* zp = (const f32x4*)zsm;  // 256 f32x4 per wave-slab
        f32x4 s = zp[tid];
#pragma unroll
        for (int w = 1; w < 16; ++w) s += zp[w * 256 + tid];
        s16x4 o;
#pragma unroll
        for (int u = 0; u < 4; ++u) o[u] = f2bf(s[u]);
        const int orow = tid >> 4, ocol = (tid & 15) << 2;
        *(s16x4*)(zb + (m0 + orow) * 64 + ocol) = o;
    }
}

// ---------------- GEMM2: C = zb(8192xK) * B4t(4096xK)^T + bias (proven r8) --
#define BM 128
#define BN 128
#define BK 32

template <int K>
__global__ __launch_bounds__(256) void gemm_bias_kernel(
    const short* __restrict__ A,    // M x K bf16
    const short* __restrict__ Bt,   // N x K bf16
    const float* __restrict__ bias,
    float* __restrict__ C) {
    constexpr int N = 4096;
    __shared__ __align__(16) char smem[16384];  // staging (8K+8K), epilogue 16K
    short* As = (short*)smem;
    short* Bs = (short*)(smem + 8192);
    float* eps = (float*)smem;

    const int tid  = threadIdx.x;
    const int wave = tid >> 6;
    const int lane = tid & 63;

    const int bid = blockIdx.x;
    const int wg  = (bid & 7) * 256 + (bid >> 3);  // 2048 % 8 == 0, bijective
    const int m0 = (wg >> 5) * BM;
    const int n0 = (wg & 31) * BN;

    const int c0i = tid;
    const int c1i = 256 + tid;
    const short* gA0 = A  + (m0 + (c0i >> 2)) * K + ((c0i & 3) << 3);
    const short* gA1 = A  + (m0 + (c1i >> 2)) * K + ((c1i & 3) << 3);
    const short* gB0 = Bt + (n0 + (c0i >> 2)) * K + ((c0i & 3) << 3);
    const short* gB1 = Bt + (n0 + (c1i >> 2)) * K + ((c1i & 3) << 3);
    short* lA0 = As + wave * 512;
    short* lA1 = As + 2048 + wave * 512;
    short* lB0 = Bs + wave * 512;
    short* lB1 = Bs + 2048 + wave * 512;

    const int wr = (wave >> 1) << 6;
    const int wc = (wave & 1) << 6;
    const int r16 = lane & 15;
    const int hi  = lane >> 4;
    const int kq  = hi << 3;

    f32x4 acc[4][4] = {};

    for (int kt = 0; kt < K / BK; ++kt) {
        __builtin_amdgcn_global_load_lds((const __attribute__((address_space(1))) void*)gA0,
                                         (__attribute__((address_space(3))) void*)lA0, 16, 0, 0);
        __builtin_amdgcn_global_load_lds((const __attribute__((address_space(1))) void*)gA1,
                                         (__attribute__((address_space(3))) void*)lA1, 16, 0, 0);
        __builtin_amdgcn_global_load_lds((const __attribute__((address_space(1))) void*)gB0,
                                         (__attribute__((address_space(3))) void*)lB0, 16, 0, 0);
        __builtin_amdgcn_global_load_lds((const __attribute__((address_space(1))) void*)gB1,
                                         (__attribute__((address_space(3))) void*)lB1, 16, 0, 0);
        gA0 += BK; gA1 += BK; gB0 += BK; gB1 += BK;
        __syncthreads();

        short8 a[4], b[4];
#pragma unroll
        for (int f = 0; f < 4; ++f) {
            a[f] = *(const short8*)(As + (wr + f * 16 + r16) * BK + kq);
            b[f] = *(const short8*)(Bs + (wc + f * 16 + r16) * BK + kq);
        }
#pragma unroll
        for (int i = 0; i < 4; ++i)
#pragma unroll
            for (int j = 0; j < 4; ++j)
                acc[i][j] = __builtin_amdgcn_mfma_f32_16x16x32_bf16(
                    a[i], b[j], acc[i][j], 0, 0, 0);
        __syncthreads();
    }

    // ---- epilogue: LDS transpose (barriered) -> 256B-contiguous stores -----
    float* slab = eps + wave * 1024;  // per-wave 4 KB slab
    const f32x4 bzv = *(const f32x4*)(bias + n0 + wc + (r16 << 2));
#pragma unroll
    for (int i = 0; i < 4; ++i) {
        __syncthreads();   // previous iteration's reads (and K-loop) complete
#pragma unroll
        for (int j = 0; j < 4; ++j)
#pragma unroll
            for (int u = 0; u < 4; ++u)
                slab[((hi << 2) + u) * 64 + j * 16 + r16] = acc[i][j][u];
        __syncthreads();   // cross-lane transpose: writes visible to reads
#pragma unroll
        for (int c = 0; c < 4; ++c) {
            const int lrow = (c << 2) + hi;                 // 0..15
            f32x4 v = *(const f32x4*)(slab + lrow * 64 + (r16 << 2));
            v += bzv;
            const long row = m0 + wr + i * 16 + lrow;
            *(f32x4*)(C + row * N + n0 + wc + (r16 << 2)) = v;
        }
    }
}

// ---------------------------------------------------------------------------
extern "C" void kernel_launch(void* const* d_in, const int* in_sizes, int n_in,
                              void* d_out, int out_size, void* d_ws, size_t ws_size,
                              hipStream_t stream) {
    const float* x    = (const float*)d_in[0];
    const float* c0   = (const float*)d_in[1];
    const float* c1   = (const float*)d_in[2];
    const float* c2   = (const float*)d_in[3];
    const float* c3   = (const float*)d_in[4];
    const float* c4   = (const float*)d_in[5];
    const float* c5   = (const float*)d_in[6];
    const float* c6   = (const float*)d_in[7];
    const float* c7   = (const float*)d_in[8];
    const float* bias = (const float*)d_in[9];
    float* out = (float*)d_out;

    char* ws = (char*)d_ws;
    short* zb  = (short*)ws;                               // 8192*64*2 = 1 MiB
    short* A4f = (short*)(ws + (1u << 20));                // 512 KiB (frag-ordered)
    short* B4t = (short*)(ws + (1u << 20) + (512u << 10)); // 4096*64*2 = 512 KiB

    tt_chain_fused<<<1536, 256, 0, stream>>>(c0, c1, c2, c3, c4, c5, c6, c7,
                                             A4f, B4t);
    gemm1_v2<<<512, 1024, 0, stream>>>(x, A4f, zb);
    gemm_bias_kernel<64><<<2048, 256, 0, stream>>>(zb, B4t, bias, out);
}